// Round 22
// baseline (69.943 us; speedup 1.0000x reference)
//
#include <hip/hip_runtime.h>
#include <hip/hip_bf16.h>

#define NROWS 8192
#define DIM 512
#define ROWB 256        // fp4 row bytes
#define NCLASS 100
#define NSLICE 32       // column slices of 256
#define NT 4            // 64-row B tiles per slice
#define INV_TEMP 14.285714285714286f
#define M0 14.285714285714286f
#define K2C  20.609929155556663f    // (1/T)*log2(e)
#define K2CS 0.08050753576389321f   // K2C/256 (values stored x16 -> acc = 256*sim)
#define PSCL 0.05580357142857143f   // INV_TEMP/256

typedef float f32x4 __attribute__((ext_vector_type(4)));
typedef int   i32x8 __attribute__((ext_vector_type(8)));

// ws layout (bytes)
#define OFF_FB   0u            // 8192*256 = 2097152 (fp4, natural nibble order, x16 scaled)
#define OFF_SP   2097152u      // 32*8192*4 = 1048576 (slot-major exp-sums)
#define OFF_PP   3145728u      // 32*8192*4 = 1048576 (slot-major masked raw-sim sums)
#define OFF_CNT  4194304u      // 100*4
#define OFF_RV   4194816u      // 2048*4

#define AS1(p) ((const __attribute__((address_space(1))) void*)(p))
#define AS3(p) ((__attribute__((address_space(3))) void*)(p))

// FP4 layout: element e of a row lives at nibble e (natural order). The MFMA dot
// is correct under ANY element->(kb,kg,slot) bijection applied identically to A
// and B — so lane kg reads chunk kb*64+kg*16 (32 nibbles) with no permutation.

// ---- 1. L2-normalize rows -> fp4 e2m1 (x16); last block does label hist ----
__global__ void norm_kernel(const float* __restrict__ F, const int* __restrict__ labels,
                            unsigned char* __restrict__ Fb, int* __restrict__ cnt) {
    __shared__ int h[NCLASS];
    if (blockIdx.x == NROWS / 4) {               // histogram block
        if (threadIdx.x < NCLASS) h[threadIdx.x] = 0;
        __syncthreads();
        for (int i = threadIdx.x; i < NROWS; i += 256)
            atomicAdd(&h[labels[i]], 1);
        __syncthreads();
        if (threadIdx.x < NCLASS) cnt[threadIdx.x] = h[threadIdx.x];
        return;
    }
    int row  = blockIdx.x * 4 + (threadIdx.x >> 6);
    int lane = threadIdx.x & 63;
    const float4* src = (const float4*)(F + (size_t)row * DIM);
    float4 a = src[lane * 2];
    float4 b = src[lane * 2 + 1];
    float ss = a.x*a.x + a.y*a.y + a.z*a.z + a.w*a.w
             + b.x*b.x + b.y*b.y + b.z*b.z + b.w*b.w;
    #pragma unroll
    for (int off = 32; off; off >>= 1) ss += __shfl_xor(ss, off);
    float inv = 16.0f / sqrtf(ss);               // x16 scale folded into constants
    float x[8] = {a.x*inv, a.y*inv, a.z*inv, a.w*inv,
                  b.x*inv, b.y*inv, b.z*inv, b.w*inv};
    unsigned int pk = 0;
    #pragma unroll
    for (int k = 0; k < 8; ++k) {
        float ax = fabsf(x[k]);
        // e2m1 grid {0,.5,1,1.5,2,3,4,6}; thresholds at midpoints
        unsigned c = (unsigned)(ax >= 0.25f) + (unsigned)(ax >= 0.75f)
                   + (unsigned)(ax >= 1.25f) + (unsigned)(ax >= 1.75f)
                   + (unsigned)(ax >= 2.5f)  + (unsigned)(ax >= 3.5f)
                   + (unsigned)(ax >= 5.0f);
        c |= (x[k] < 0.f) ? 8u : 0u;
        pk |= c << (k * 4);
    }
    *(unsigned int*)(Fb + (size_t)row * ROWB + lane * 4) = pk;
}

// ---- 2. MX-FP4 MFMA similarity: exp-sum + label-masked raw-sim sum; m=4,
//      256-col slices -> grid 1024 -> 3-4 blocks/CU for latency hiding ----
__global__ __launch_bounds__(256, 1)
void simstats_kernel(const unsigned char* __restrict__ Fb, const int* __restrict__ labels,
                     float* __restrict__ Sp, float* __restrict__ Pp) {
    __shared__ unsigned char lds[2][64][ROWB];   // 2 x 16 KiB dbuf
    __shared__ int slab[256];                    // column labels of this slice
    int orig  = blockIdx.x;
    int bid   = (orig & 7) * 128 + (orig >> 3);  // XCD-chunked swizzle (1024%8==0)
    int strip = bid >> 5;                        // 0..31 (256 rows)
    int slice = bid & 31;                        // 0..31 (256 cols)
    int w     = threadIdx.x >> 6;                // 0..3
    int lane  = threadIdx.x & 63;
    int col   = lane & 15;
    int kg    = lane >> 4;                       // 0..3
    int c7    = col & 7;
    int r0    = strip * 256 + w * 64;
    int jb0   = slice * 256;

    slab[threadIdx.x] = labels[jb0 + threadIdx.x];

    // A fragments pinned: 4 m-tiles x 4 K128-blocks x 16B payload
    i32x8 afr[4][4];
    #pragma unroll
    for (int m = 0; m < 4; ++m) {
        const unsigned char* arow = Fb + (size_t)(r0 + m * 16 + col) * ROWB;
        #pragma unroll
        for (int kb = 0; kb < 4; ++kb) {
            uint4 q = *(const uint4*)(arow + kb * 64 + kg * 16);
            i32x8 v = {0, 0, 0, 0, 0, 0, 0, 0};
            v[0] = (int)q.x; v[1] = (int)q.y; v[2] = (int)q.z; v[3] = (int)q.w;
            afr[m][kb] = v;
        }
    }

    // labels of this lane's 16 output rows (C layout: row = m*16 + kg*4 + r)
    int labrow[4][4];
    #pragma unroll
    for (int m = 0; m < 4; ++m)
        #pragma unroll
        for (int r = 0; r < 4; ++r)
            labrow[m][r] = labels[r0 + m * 16 + kg * 4 + r];

    // stage 64-row x 256B tile (4 gload_lds/thread); chunk-swizzled source (chunk ^= row&7)
    auto stage = [&](int b, int t) {
        #pragma unroll
        for (int i = 0; i < 4; ++i) {
            int nb = i * 16 + w * 4;                 // wave-uniform base row (4 rows/issue)
            int n  = nb + (lane >> 4);
            int c  = lane & 15;
            const unsigned char* src =
                Fb + (size_t)(jb0 + t * 64 + n) * ROWB + ((c ^ (n & 7)) << 4);
            __builtin_amdgcn_global_load_lds(AS1(src), AS3(&lds[b][nb][0]), 16, 0, 0);
        }
    };

    float S[4][4] = {{0.f,0.f,0.f,0.f},{0.f,0.f,0.f,0.f},
                     {0.f,0.f,0.f,0.f},{0.f,0.f,0.f,0.f}};
    float P[4][4] = {{0.f,0.f,0.f,0.f},{0.f,0.f,0.f,0.f},
                     {0.f,0.f,0.f,0.f},{0.f,0.f,0.f,0.f}};

    auto compute = [&](int b, int t) {
        #pragma unroll
        for (int ct = 0; ct < 4; ++ct) {
            const unsigned char* rowbase = &lds[b][ct * 16 + col][0];
            int lcc = slab[t * 64 + ct * 16 + col];      // ds_read, lgkm path only
            f32x4 acc[4] = {{0.f,0.f,0.f,0.f},{0.f,0.f,0.f,0.f},
                            {0.f,0.f,0.f,0.f},{0.f,0.f,0.f,0.f}};
            #pragma unroll
            for (int kb = 0; kb < 4; ++kb) {
                uint4 q = *(const uint4*)(rowbase + (((kb * 4 + kg) ^ c7) << 4));
                i32x8 bop = {0, 0, 0, 0, 0, 0, 0, 0};
                bop[0] = (int)q.x; bop[1] = (int)q.y; bop[2] = (int)q.z; bop[3] = (int)q.w;
                #pragma unroll
                for (int m = 0; m < 4; ++m)
                    acc[m] = __builtin_amdgcn_mfma_scale_f32_16x16x128_f8f6f4(
                        afr[m][kb], bop, acc[m],
                        4, 4,                      // cbsz=fp4(e2m1), blgp=fp4(e2m1)
                        0, 0x7F7F7F7F,             // scaleA = 1.0
                        0, 0x7F7F7F7F);            // scaleB = 1.0
            }
            #pragma unroll
            for (int m = 0; m < 4; ++m)
                #pragma unroll
                for (int r = 0; r < 4; ++r) {
                    S[m][r] += __builtin_amdgcn_exp2f(fmaf(acc[m][r], K2CS, -K2C));
                    P[m][r] += (labrow[m][r] == lcc) ? acc[m][r] : 0.f;
                }
        }
    };

    stage(0, 0);
    for (int t = 0; t < NT; ++t) {
        __syncthreads();                       // staged tile t visible; prev reads drained
        if (t + 1 < NT) stage((t + 1) & 1, t + 1);
        compute(t & 1, t);
    }

    // row-sums: reduce across the 16 col-lanes of each kg group
    #pragma unroll
    for (int off = 1; off < 16; off <<= 1) {
        #pragma unroll
        for (int m = 0; m < 4; ++m)
            #pragma unroll
            for (int r = 0; r < 4; ++r) {
                S[m][r] += __shfl_xor(S[m][r], off);
                P[m][r] += __shfl_xor(P[m][r], off);
            }
    }
    if (col == 0) {
        #pragma unroll
        for (int m = 0; m < 4; ++m)
            #pragma unroll
            for (int r = 0; r < 4; ++r) {
                size_t idx = (size_t)slice * NROWS + r0 + m * 16 + kg * 4 + r;
                Sp[idx] = S[m][r];
                Pp[idx] = P[m][r];
            }
    }
}

// ---- 3. per-row loss term: one wave per row; block partial sums ----
__global__ void finalize_kernel(const unsigned char* __restrict__ Fb,
                                const int* __restrict__ labels,
                                const float* __restrict__ Sp,
                                const float* __restrict__ Pp,
                                const int* __restrict__ cnt,
                                float* __restrict__ rv) {
    int i    = blockIdx.x * 4 + (threadIdx.x >> 6);
    int lane = threadIdx.x & 63;
    int lab  = labels[i];
    unsigned int pk = *(const unsigned int*)(Fb + (size_t)i * ROWB + lane * 4);
    // ssr = sum of squared STORED fp4 values (x16): squares all exact in fp32
    // -> bit-matches the MFMA diagonal accumulation.
    float ssr = 0.f;
    #pragma unroll
    for (int k = 0; k < 8; ++k) {
        unsigned mth = (pk >> (k * 4)) & 7u;       // magnitude code (sign irrelevant)
        int   e    = (int)(mth >> 1);
        float half = 0.5f * (float)(mth & 1u);
        float base = e ? (1.0f + half) : half;
        float g    = base * __builtin_amdgcn_exp2f((float)(e ? e - 1 : 0));
        ssr = fmaf(g, g, ssr);
    }
    float sadd = (lane < NSLICE) ? Sp[(size_t)lane * NROWS + i] : 0.f;
    float padd = (lane < NSLICE) ? Pp[(size_t)lane * NROWS + i] : 0.f;
    #pragma unroll
    for (int off = 32; off; off >>= 1) {
        ssr  += __shfl_xor(ssr, off);
        sadd += __shfl_xor(sadd, off);
        padd += __shfl_xor(padd, off);
    }
    __shared__ float pbuf[4];
    if (lane == 0) {
        float cntf  = (float)cnt[lab];
        float eself = __builtin_amdgcn_exp2f(fmaf(ssr, K2CS, -K2C));  // exact diag match
        float S     = sadd - eself + 1e-12f;
        pbuf[threadIdx.x >> 6] = M0 + logf(S) - (padd * PSCL) / cntf;
    }
    __syncthreads();
    if (threadIdx.x == 0) rv[blockIdx.x] = pbuf[0] + pbuf[1] + pbuf[2] + pbuf[3];
}

// ---- 4. scalar reduce over 2048 block partials ----
__global__ void reduce_kernel(const float* __restrict__ rv, float* __restrict__ out) {
    float s = 0.f;
    #pragma unroll
    for (int i = threadIdx.x; i < NROWS / 4; i += 256) s += rv[i];
    #pragma unroll
    for (int off = 32; off; off >>= 1) s += __shfl_xor(s, off);
    __shared__ float buf[4];
    int w = threadIdx.x >> 6;
    if ((threadIdx.x & 63) == 0) buf[w] = s;
    __syncthreads();
    if (threadIdx.x == 0) out[0] = (buf[0] + buf[1] + buf[2] + buf[3]) * (1.0f / (float)NROWS);
}

extern "C" void kernel_launch(void* const* d_in, const int* in_sizes, int n_in,
                              void* d_out, int out_size, void* d_ws, size_t ws_size,
                              hipStream_t stream) {
    const float* F      = (const float*)d_in[0];
    const int*   labels = (const int*)d_in[1];
    float*       out    = (float*)d_out;
    char*        ws     = (char*)d_ws;

    unsigned char* Fb   = (unsigned char*)(ws + OFF_FB);
    float*         Sp   = (float*)(ws + OFF_SP);
    float*         Pp   = (float*)(ws + OFF_PP);
    int*           cnt  = (int*)(ws + OFF_CNT);
    float*         rv   = (float*)(ws + OFF_RV);

    norm_kernel<<<NROWS / 4 + 1, 256, 0, stream>>>(F, labels, Fb, cnt);
    simstats_kernel<<<1024, 256, 0, stream>>>(Fb, labels, Sp, Pp);
    finalize_kernel<<<NROWS / 4, 256, 0, stream>>>(Fb, labels, Sp, Pp, cnt, rv);
    reduce_kernel<<<1, 256, 0, stream>>>(rv, out);
}

// Round 23
// 54.378 us; speedup vs baseline: 1.2862x; 1.2862x over previous
//
#include <hip/hip_runtime.h>
#include <hip/hip_bf16.h>

#define NROWS 8192
#define DIM 512
#define ROWB 256        // fp4 row bytes
#define NCLASS 100
#define NSLICE 16       // column slices of 512
#define NT 4            // 128-row B tiles per slice
#define INV_TEMP 14.285714285714286f
#define M0 14.285714285714286f
#define K2C  20.609929155556663f    // (1/T)*log2(e)
#define K2CS 0.08050753576389321f   // K2C/256 (values stored x16 -> acc = 256*sim)
#define PSCL 0.05580357142857143f   // INV_TEMP/256

typedef float f32x4 __attribute__((ext_vector_type(4)));
typedef int   i32x8 __attribute__((ext_vector_type(8)));

// ws layout (bytes)
#define OFF_FB   0u            // 8192*256 = 2097152 (fp4, natural nibble order, x16 scaled)
#define OFF_SP   2097152u      // 16*8192*4 = 524288 (slot-major exp-sums)
#define OFF_PP   2621440u      // 16*8192*4 = 524288 (slot-major masked raw-sim sums)
#define OFF_CNT  3145728u      // 100*4
#define OFF_RV   3146240u      // 2048*4

#define AS1(p) ((const __attribute__((address_space(1))) void*)(p))
#define AS3(p) ((__attribute__((address_space(3))) void*)(p))

// FP4 layout: element e of a row lives at nibble e (natural order). The MFMA dot
// is correct under ANY element->(kb,kg,slot) bijection applied identically to A
// and B — so lane kg reads chunk kb*64+kg*16 (32 nibbles) with no permutation.

// ---- 1. L2-normalize rows -> fp4 e2m1 (x16); last block does label hist ----
__global__ void norm_kernel(const float* __restrict__ F, const int* __restrict__ labels,
                            unsigned char* __restrict__ Fb, int* __restrict__ cnt) {
    __shared__ int h[NCLASS];
    if (blockIdx.x == NROWS / 4) {               // histogram block
        if (threadIdx.x < NCLASS) h[threadIdx.x] = 0;
        __syncthreads();
        for (int i = threadIdx.x; i < NROWS; i += 256)
            atomicAdd(&h[labels[i]], 1);
        __syncthreads();
        if (threadIdx.x < NCLASS) cnt[threadIdx.x] = h[threadIdx.x];
        return;
    }
    int row  = blockIdx.x * 4 + (threadIdx.x >> 6);
    int lane = threadIdx.x & 63;
    const float4* src = (const float4*)(F + (size_t)row * DIM);
    float4 a = src[lane * 2];
    float4 b = src[lane * 2 + 1];
    float ss = a.x*a.x + a.y*a.y + a.z*a.z + a.w*a.w
             + b.x*b.x + b.y*b.y + b.z*b.z + b.w*b.w;
    #pragma unroll
    for (int off = 32; off; off >>= 1) ss += __shfl_xor(ss, off);
    float inv = 16.0f / sqrtf(ss);               // x16 scale folded into constants
    float x[8] = {a.x*inv, a.y*inv, a.z*inv, a.w*inv,
                  b.x*inv, b.y*inv, b.z*inv, b.w*inv};
    unsigned int pk = 0;
    #pragma unroll
    for (int k = 0; k < 8; ++k) {
        float ax = fabsf(x[k]);
        // e2m1 grid {0,.5,1,1.5,2,3,4,6}; thresholds at midpoints
        unsigned c = (unsigned)(ax >= 0.25f) + (unsigned)(ax >= 0.75f)
                   + (unsigned)(ax >= 1.25f) + (unsigned)(ax >= 1.75f)
                   + (unsigned)(ax >= 2.5f)  + (unsigned)(ax >= 3.5f)
                   + (unsigned)(ax >= 5.0f);
        c |= (x[k] < 0.f) ? 8u : 0u;
        pk |= c << (k * 4);
    }
    *(unsigned int*)(Fb + (size_t)row * ROWB + lane * 4) = pk;
}

// ---- 2. MX-FP4 MFMA similarity: exp-sum + label-masked raw-sim sum; m=4,
//      128-row tiles (NT=4): half the barrier/drain events of r21 ----
__global__ __launch_bounds__(256, 1)
void simstats_kernel(const unsigned char* __restrict__ Fb, const int* __restrict__ labels,
                     float* __restrict__ Sp, float* __restrict__ Pp) {
    __shared__ unsigned char lds[2][128][ROWB];  // 2 x 32 KiB dbuf
    __shared__ int slab[512];                    // column labels of this slice
    int orig  = blockIdx.x;
    int bid   = (orig & 7) * 64 + (orig >> 3);   // XCD-chunked swizzle (512%8==0)
    int strip = bid >> 4;                        // 0..31 (256 rows)
    int slice = bid & 15;                        // 0..15 (512 cols)
    int w     = threadIdx.x >> 6;                // 0..3
    int lane  = threadIdx.x & 63;
    int col   = lane & 15;
    int kg    = lane >> 4;                       // 0..3
    int c7    = col & 7;
    int r0    = strip * 256 + w * 64;
    int jb0   = slice * 512;

    slab[threadIdx.x]       = labels[jb0 + threadIdx.x];
    slab[threadIdx.x + 256] = labels[jb0 + 256 + threadIdx.x];

    // A fragments pinned: 4 m-tiles x 4 K128-blocks x 16B payload
    i32x8 afr[4][4];
    #pragma unroll
    for (int m = 0; m < 4; ++m) {
        const unsigned char* arow = Fb + (size_t)(r0 + m * 16 + col) * ROWB;
        #pragma unroll
        for (int kb = 0; kb < 4; ++kb) {
            uint4 q = *(const uint4*)(arow + kb * 64 + kg * 16);
            i32x8 v = {0, 0, 0, 0, 0, 0, 0, 0};
            v[0] = (int)q.x; v[1] = (int)q.y; v[2] = (int)q.z; v[3] = (int)q.w;
            afr[m][kb] = v;
        }
    }

    // labels of this lane's 16 output rows (C layout: row = m*16 + kg*4 + r)
    int labrow[4][4];
    #pragma unroll
    for (int m = 0; m < 4; ++m)
        #pragma unroll
        for (int r = 0; r < 4; ++r)
            labrow[m][r] = labels[r0 + m * 16 + kg * 4 + r];

    // stage 128-row x 256B tile (8 gload_lds/thread, 4 rows per wave-issue);
    // chunk-swizzled source (chunk ^= row&7), LDS linear
    auto stage = [&](int b, int t) {
        #pragma unroll
        for (int i = 0; i < 8; ++i) {
            int nb = w * 32 + i * 4;                 // wave-uniform base row (4 rows/issue)
            int n  = nb + (lane >> 4);
            int c  = lane & 15;
            const unsigned char* src =
                Fb + (size_t)(jb0 + t * 128 + n) * ROWB + ((c ^ (n & 7)) << 4);
            __builtin_amdgcn_global_load_lds(AS1(src), AS3(&lds[b][nb][0]), 16, 0, 0);
        }
    };

    float S[4][4] = {{0.f,0.f,0.f,0.f},{0.f,0.f,0.f,0.f},
                     {0.f,0.f,0.f,0.f},{0.f,0.f,0.f,0.f}};
    float P[4][4] = {{0.f,0.f,0.f,0.f},{0.f,0.f,0.f,0.f},
                     {0.f,0.f,0.f,0.f},{0.f,0.f,0.f,0.f}};

    auto compute = [&](int b, int t) {
        #pragma unroll
        for (int ct = 0; ct < 8; ++ct) {
            const unsigned char* rowbase = &lds[b][ct * 16 + col][0];
            int lcc = slab[t * 128 + ct * 16 + col];     // ds_read, lgkm path only
            f32x4 acc[4] = {{0.f,0.f,0.f,0.f},{0.f,0.f,0.f,0.f},
                            {0.f,0.f,0.f,0.f},{0.f,0.f,0.f,0.f}};
            #pragma unroll
            for (int kb = 0; kb < 4; ++kb) {
                uint4 q = *(const uint4*)(rowbase + (((kb * 4 + kg) ^ c7) << 4));
                i32x8 bop = {0, 0, 0, 0, 0, 0, 0, 0};
                bop[0] = (int)q.x; bop[1] = (int)q.y; bop[2] = (int)q.z; bop[3] = (int)q.w;
                #pragma unroll
                for (int m = 0; m < 4; ++m)
                    acc[m] = __builtin_amdgcn_mfma_scale_f32_16x16x128_f8f6f4(
                        afr[m][kb], bop, acc[m],
                        4, 4,                      // cbsz=fp4(e2m1), blgp=fp4(e2m1)
                        0, 0x7F7F7F7F,             // scaleA = 1.0
                        0, 0x7F7F7F7F);            // scaleB = 1.0
            }
            #pragma unroll
            for (int m = 0; m < 4; ++m)
                #pragma unroll
                for (int r = 0; r < 4; ++r) {
                    S[m][r] += __builtin_amdgcn_exp2f(fmaf(acc[m][r], K2CS, -K2C));
                    P[m][r] += (labrow[m][r] == lcc) ? acc[m][r] : 0.f;
                }
        }
    };

    stage(0, 0);
    for (int t = 0; t < NT; ++t) {
        __syncthreads();                       // staged tile t visible; prev reads drained
        if (t + 1 < NT) stage((t + 1) & 1, t + 1);
        compute(t & 1, t);
    }

    // row-sums: reduce across the 16 col-lanes of each kg group
    #pragma unroll
    for (int off = 1; off < 16; off <<= 1) {
        #pragma unroll
        for (int m = 0; m < 4; ++m)
            #pragma unroll
            for (int r = 0; r < 4; ++r) {
                S[m][r] += __shfl_xor(S[m][r], off);
                P[m][r] += __shfl_xor(P[m][r], off);
            }
    }
    if (col == 0) {
        #pragma unroll
        for (int m = 0; m < 4; ++m)
            #pragma unroll
            for (int r = 0; r < 4; ++r) {
                size_t idx = (size_t)slice * NROWS + r0 + m * 16 + kg * 4 + r;
                Sp[idx] = S[m][r];
                Pp[idx] = P[m][r];
            }
    }
}

// ---- 3. per-row loss term: one wave per row; block partial sums ----
__global__ void finalize_kernel(const unsigned char* __restrict__ Fb,
                                const int* __restrict__ labels,
                                const float* __restrict__ Sp,
                                const float* __restrict__ Pp,
                                const int* __restrict__ cnt,
                                float* __restrict__ rv) {
    int i    = blockIdx.x * 4 + (threadIdx.x >> 6);
    int lane = threadIdx.x & 63;
    int lab  = labels[i];
    unsigned int pk = *(const unsigned int*)(Fb + (size_t)i * ROWB + lane * 4);
    // ssr = sum of squared STORED fp4 values (x16): squares all exact in fp32
    // -> bit-matches the MFMA diagonal accumulation.
    float ssr = 0.f;
    #pragma unroll
    for (int k = 0; k < 8; ++k) {
        unsigned mth = (pk >> (k * 4)) & 7u;       // magnitude code (sign irrelevant)
        int   e    = (int)(mth >> 1);
        float half = 0.5f * (float)(mth & 1u);
        float base = e ? (1.0f + half) : half;
        float g    = base * __builtin_amdgcn_exp2f((float)(e ? e - 1 : 0));
        ssr = fmaf(g, g, ssr);
    }
    float sadd = (lane < NSLICE) ? Sp[(size_t)lane * NROWS + i] : 0.f;
    float padd = (lane < NSLICE) ? Pp[(size_t)lane * NROWS + i] : 0.f;
    #pragma unroll
    for (int off = 32; off; off >>= 1) {
        ssr  += __shfl_xor(ssr, off);
        sadd += __shfl_xor(sadd, off);
        padd += __shfl_xor(padd, off);
    }
    __shared__ float pbuf[4];
    if (lane == 0) {
        float cntf  = (float)cnt[lab];
        float eself = __builtin_amdgcn_exp2f(fmaf(ssr, K2CS, -K2C));  // exact diag match
        float S     = sadd - eself + 1e-12f;
        pbuf[threadIdx.x >> 6] = M0 + logf(S) - (padd * PSCL) / cntf;
    }
    __syncthreads();
    if (threadIdx.x == 0) rv[blockIdx.x] = pbuf[0] + pbuf[1] + pbuf[2] + pbuf[3];
}

// ---- 4. scalar reduce over 2048 block partials ----
__global__ void reduce_kernel(const float* __restrict__ rv, float* __restrict__ out) {
    float s = 0.f;
    #pragma unroll
    for (int i = threadIdx.x; i < NROWS / 4; i += 256) s += rv[i];
    #pragma unroll
    for (int off = 32; off; off >>= 1) s += __shfl_xor(s, off);
    __shared__ float buf[4];
    int w = threadIdx.x >> 6;
    if ((threadIdx.x & 63) == 0) buf[w] = s;
    __syncthreads();
    if (threadIdx.x == 0) out[0] = (buf[0] + buf[1] + buf[2] + buf[3]) * (1.0f / (float)NROWS);
}

extern "C" void kernel_launch(void* const* d_in, const int* in_sizes, int n_in,
                              void* d_out, int out_size, void* d_ws, size_t ws_size,
                              hipStream_t stream) {
    const float* F      = (const float*)d_in[0];
    const int*   labels = (const int*)d_in[1];
    float*       out    = (float*)d_out;
    char*        ws     = (char*)d_ws;

    unsigned char* Fb   = (unsigned char*)(ws + OFF_FB);
    float*         Sp   = (float*)(ws + OFF_SP);
    float*         Pp   = (float*)(ws + OFF_PP);
    int*           cnt  = (int*)(ws + OFF_CNT);
    float*         rv   = (float*)(ws + OFF_RV);

    norm_kernel<<<NROWS / 4 + 1, 256, 0, stream>>>(F, labels, Fb, cnt);
    simstats_kernel<<<512, 256, 0, stream>>>(Fb, labels, Sp, Pp);
    finalize_kernel<<<NROWS / 4, 256, 0, stream>>>(Fb, labels, Sp, Pp, cnt, rv);
    reduce_kernel<<<1, 256, 0, stream>>>(rv, out);
}